// Round 9
// baseline (1497.854 us; speedup 1.0000x reference)
//
#include <hip/hip_runtime.h>
#include <math.h>

#define NEG_SLOPE 0.2f
#define CAP 128      // bucket capacity per dst (mean deg ~33)
#define BCAP 6144    // bin staging capacity (mean ~4350/bin)

// ---- monotonic float<->uint encoding for atomicMax on floats ----
__device__ __forceinline__ unsigned enc_f(float f) {
    unsigned b = __float_as_uint(f);
    return (b & 0x80000000u) ? ~b : (b | 0x80000000u);
}
__device__ __forceinline__ float dec_f(unsigned u) {
    return (u & 0x80000000u) ? __uint_as_float(u ^ 0x80000000u) : __uint_as_float(~u);
}
#define ENC_NEG_INF 0x007FFFFFu

// ---- bf16 pack/unpack (messages only; all accumulation fp32) ----
__device__ __forceinline__ unsigned short f2bf(float f) {
    unsigned u = __float_as_uint(f);
    u += 0x7fffu + ((u >> 16) & 1u);  // round-to-nearest-even
    return (unsigned short)(u >> 16);
}
__device__ __forceinline__ float bf2f(unsigned short b) {
    return __uint_as_float(((unsigned)b) << 16);
}

static inline int nblk(long total, int b) { return (int)((total + b - 1) / b); }

// ================= init (ws poisoned 0xAA every call) =================
__global__ void init_kernel(int* bincnt, float* bn, unsigned* menc, int nbin) {
    int i = blockIdx.x * blockDim.x + threadIdx.x;
    if (i < nbin) bincnt[i] = 0;
    if (i < 256) bn[i] = 0.f;
    if (i < 16) menc[i] = ENC_NEG_INF;
}

// ================= pass 1: bin edges by dst>>7 =================
__global__ void bin_kernel(const int* __restrict__ srcs, const int* __restrict__ dsts,
                           int E_, int EA, int nbin, int* bincnt, unsigned* __restrict__ binbuf) {
    __shared__ int lh[512];
    __shared__ int lbase[512];
    int tid = threadIdx.x;
    for (int i = tid; i < nbin; i += 256) lh[i] = 0;
    __syncthreads();
    int chunk = (EA + gridDim.x - 1) / gridDim.x;
    int e0 = blockIdx.x * chunk;
    int e1 = e0 + chunk; if (e1 > EA) e1 = EA;
    for (int i = e0 + tid; i < e1; i += 256) {
        int d = (i < E_) ? dsts[i] : (i - E_);
        atomicAdd(&lh[d >> 7], 1);
    }
    __syncthreads();
    for (int i = tid; i < nbin; i += 256) {
        lbase[i] = atomicAdd(&bincnt[i], lh[i]);
        lh[i] = 0;
    }
    __syncthreads();
    for (int i = e0 + tid; i < e1; i += 256) {
        int s, d;
        if (i < E_) { s = srcs[i]; d = dsts[i]; } else { s = d = i - E_; }
        int b = d >> 7;
        int pos = lbase[b] + atomicAdd(&lh[b], 1);
        if (pos < BCAP) binbuf[(size_t)b * BCAP + pos] = ((unsigned)s << 16) | (unsigned)d;
    }
}

// ================= pass 2: per-bin bucket CSR in LDS =================
__global__ void build_kernel(const unsigned* __restrict__ binbuf, const int* __restrict__ bincnt,
                             unsigned short* __restrict__ esrc, int* __restrict__ cnt, int n) {
    __shared__ unsigned short slab[128 * CAP];  // 32 KB
    __shared__ int lcnt[128];
    int tid = threadIdx.x;
    int b = blockIdx.x, d0 = b << 7;
    if (tid < 128) lcnt[tid] = 0;
    __syncthreads();
    int nb = bincnt[b]; if (nb > BCAP) nb = BCAP;
    for (int i = tid; i < nb; i += 256) {
        unsigned u = binbuf[(size_t)b * BCAP + i];
        int s = (int)(u >> 16);
        int ld = (int)(u & 0xffffu) - d0;
        int pos = atomicAdd(&lcnt[ld], 1);
        if (pos < CAP) slab[ld * CAP + pos] = (unsigned short)s;
    }
    __syncthreads();
    const uint4* sl = (const uint4*)slab;
    uint4* outp = (uint4*)esrc;
    for (int i = tid; i < 128 * CAP / 8; i += 256) {
        int r = i >> 4;
        if (d0 + r < n) outp[(size_t)(d0 + r) * (CAP / 8) + (i & 15)] = sl[i];
    }
    if (tid < 128 && d0 + tid < n) cnt[d0 + tid] = lcnt[tid];
}

// ===== GEMM (fp32 in, BF16 out) + input-BN/ReLU + alpha epilogue + fused alpha-max =====
// Barrier-free K-loop: per-wave private X slab (intra-wave lgkm ordering), W padded KP=K+2
// read as float2 (2-way bank aliasing = free). NOTE (R8 post-mortem): do NOT use
// __builtin_amdgcn_global_load_lds here — it produced 2.1 GB of phantom HBM traffic
// (653 us vs 67 us) on this structure; plain float4 staging is the fast path.
template <int K, bool BN>
__global__ void gemm_alpha_kernel(const float* __restrict__ X, const float* __restrict__ W,
                                  const float* __restrict__ a_s, const float* __restrict__ a_d,
                                  unsigned short* __restrict__ Hout, float* __restrict__ as_o,
                                  float* __restrict__ ad_o, unsigned* menc_, int n,
                                  const float* __restrict__ bnsum,
                                  const float* __restrict__ bnsq,
                                  const float* __restrict__ g,
                                  const float* __restrict__ beta) {
    constexpr int M = 64, KP = K + 2;
    __shared__ __align__(16) float Wt[M * KP];
    __shared__ __align__(16) float scale[K];
    __shared__ __align__(16) float shift[K];
    __shared__ __align__(16) float Xs[4][4 * K];

    int tid = threadIdx.x;
    for (int i = tid; i < K * M; i += 256) {
        int k = i >> 6, col = i & 63;
        Wt[col * KP + k] = W[i];  // write stride KP: 2-way bank alias, free
    }
    if (BN) {
        float inv_n = 1.0f / (float)n;
        for (int i = tid; i < K; i += 256) {
            float mu = bnsum[i] * inv_n;
            float var = bnsq[i] * inv_n - mu * mu;
            float sc = rsqrtf(var + 1e-5f) * g[i];
            scale[i] = sc;
            shift[i] = beta[i] - mu * sc;
        }
    }
    __syncthreads();  // only barrier: Wt/scale staging

    int lane = tid & 63, wv = tid >> 6;
    float asv = a_s[lane];
    float adv = a_d[lane];
    float* Xw = Xs[wv];
    const float2* wcol = (const float2*)(Wt + lane * KP);  // lane*KP even -> 8B aligned
    float amax = -1e30f;

    int nwaves = gridDim.x * 4;
    int ngroups = (n + 3) >> 2;

    for (int grp = blockIdx.x * 4 + wv; grp < ngroups; grp += nwaves) {
        int node0 = grp * 4;
        int nn = n - node0 < 4 ? n - node0 : 4;

        for (int v = lane; v < (nn * K) >> 2; v += 64) {
            float4 xv = ((const float4*)(X + (size_t)node0 * K))[v];
            if (BN) {
                int k4 = (v * 4) % K;
                float4 sc = *(const float4*)(scale + k4);
                float4 sh = *(const float4*)(shift + k4);
                xv.x = fmaf(xv.x, sc.x, sh.x); xv.x = xv.x > 0.f ? xv.x : 0.f;
                xv.y = fmaf(xv.y, sc.y, sh.y); xv.y = xv.y > 0.f ? xv.y : 0.f;
                xv.z = fmaf(xv.z, sc.z, sh.z); xv.z = xv.z > 0.f ? xv.z : 0.f;
                xv.w = fmaf(xv.w, sc.w, sh.w); xv.w = xv.w > 0.f ? xv.w : 0.f;
            }
            ((float4*)Xw)[v] = xv;  // intra-wave RAW via lgkmcnt; no barrier
        }

        float acc[4] = {0.f, 0.f, 0.f, 0.f};
        for (int kk = 0; kk < K; kk += 4) {
            float2 w0 = wcol[kk >> 1];
            float2 w1 = wcol[(kk >> 1) + 1];
#pragma unroll
            for (int i = 0; i < 4; ++i) {
                float4 xv = *(const float4*)(Xw + i * K + kk);  // wave-uniform broadcast
                acc[i] = fmaf(xv.x, w0.x, acc[i]);
                acc[i] = fmaf(xv.y, w0.y, acc[i]);
                acc[i] = fmaf(xv.z, w1.x, acc[i]);
                acc[i] = fmaf(xv.w, w1.y, acc[i]);
            }
        }
#pragma unroll
        for (int i = 0; i < 4; ++i) {
            if (i >= nn) break;
            int node = node0 + i;
            Hout[(size_t)node * 64 + lane] = f2bf(acc[i]);
            float p1 = acc[i] * asv, p2 = acc[i] * adv;
#pragma unroll
            for (int o = 1; o < 16; o <<= 1) {
                p1 += __shfl_xor(p1, o, 64);
                p2 += __shfl_xor(p2, o, 64);
            }
            amax = fmaxf(amax, p1);
            if ((lane & 15) == 0) {
                as_o[(size_t)node * 4 + (lane >> 4)] = p1;
                ad_o[(size_t)node * 4 + (lane >> 4)] = p2;
            }
        }
    }
    if ((lane & 15) == 0) atomicMax(&menc_[lane >> 4], enc_f(amax));
}

// ====== gather64: 2 waves/node, bf16 rows (128 B = one line), 4 edges/iter ======
__global__ void gather64_kernel(const int* __restrict__ cnt,
                                const unsigned short* __restrict__ esrc,
                                const float* __restrict__ as_, const float* __restrict__ ad_,
                                const unsigned short* __restrict__ Hf,
                                const unsigned* __restrict__ menc,
                                const float* __restrict__ bias, float* __restrict__ feat, int n) {
    __shared__ __align__(16) float comb[2][2][68];
    int tid = threadIdx.x;
    int wv = tid >> 6, lane = tid & 63;
    int ns = wv >> 1, ww = wv & 1;
    int slot = lane >> 4, ql = lane & 15, hq = ql >> 2;
    int node = blockIdx.x * 2 + ns;
    bool act = node < n;

    if (act) {
        int deg = cnt[node]; if (deg > CAP) deg = CAP;
        const unsigned short* ep = esrc + (size_t)node * CAP;
        float4 adv = *(const float4*)(ad_ + (size_t)node * 4);
        float adh = (slot == 0) ? adv.x : (slot == 1) ? adv.y : (slot == 2) ? adv.z : adv.w;
        float mm = dec_f(menc[slot]) + adh;  // shift >= true segment max
        float mh = mm > 0.f ? mm : NEG_SLOPE * mm;

        float4 acc = make_float4(0.f, 0.f, 0.f, 0.f);
        float wp = 0.f;
        for (int base = ww * 16; base < deg; base += 32) {
            int lim = deg - base; if (lim > 16) lim = 16;
            int s = 0; float w = 0.f;
            if (ql < lim) {
                s = (int)ep[base + ql];
                float ev = as_[(size_t)s * 4 + slot] + adh;
                ev = ev > 0.f ? ev : NEG_SLOPE * ev;
                w = __expf(ev - mh);
            }
            wp += w;
#pragma unroll
            for (int i = 0; i < 4; ++i) {
                int cj = i * 4 + slot;
                int sj = __shfl(s, cj, 64);
                float wj = __shfl(w, hq * 16 + cj, 64);  // 0 past lim
                ushort4 hv = *(const ushort4*)(Hf + (size_t)sj * 64 + ql * 4);
                acc.x = fmaf(bf2f(hv.x), wj, acc.x);
                acc.y = fmaf(bf2f(hv.y), wj, acc.y);
                acc.z = fmaf(bf2f(hv.z), wj, acc.z);
                acc.w = fmaf(bf2f(hv.w), wj, acc.w);
            }
        }
#pragma unroll
        for (int o = 16; o < 64; o <<= 1) {
            acc.x += __shfl_xor(acc.x, o, 64);
            acc.y += __shfl_xor(acc.y, o, 64);
            acc.z += __shfl_xor(acc.z, o, 64);
            acc.w += __shfl_xor(acc.w, o, 64);
        }
#pragma unroll
        for (int o = 1; o < 16; o <<= 1) wp += __shfl_xor(wp, o, 64);
        if (slot == 0) *(float4*)&comb[ns][ww][ql * 4] = acc;
        if (ql == 0) comb[ns][ww][64 + slot] = wp;
    }
    __syncthreads();
    if (act && ww == 0) {
        float v = comb[ns][0][lane] + comb[ns][1][lane];
        float wsum = comb[ns][0][64 + (lane >> 4)] + comb[ns][1][64 + (lane >> 4)];
        feat[(size_t)node * 64 + lane] = v / (wsum + 1e-16f) + bias[lane];
    }
}

// ====== layer-2 prep: z = relu(bn(feat)) in bf16; alpha = z . (W2@a); fused max ======
__global__ void prep2_kernel(const float* __restrict__ feat, const float* __restrict__ bnsum,
                             const float* __restrict__ bnsq, const float* __restrict__ g,
                             const float* __restrict__ beta, const float* __restrict__ W2,
                             const float* __restrict__ as2v, const float* __restrict__ ad2v,
                             unsigned short* __restrict__ z, float* __restrict__ as_o,
                             float* __restrict__ ad_o, unsigned* menc_, int n) {
    __shared__ float sc[64], sh[64], vs[64], vd[64];
    int tid = threadIdx.x;
    if (tid < 64) {
        float inv_n = 1.0f / (float)n;
        float mu = bnsum[tid] * inv_n;
        float var = bnsq[tid] * inv_n - mu * mu;
        float s = rsqrtf(var + 1e-5f) * g[tid];
        sc[tid] = s;
        sh[tid] = beta[tid] - mu * s;
    } else if (tid < 128) {
        int k = tid - 64;
        float s1 = 0.f, s2 = 0.f;
        for (int j = 0; j < 40; ++j) {
            float wv = W2[k * 40 + j];
            s1 = fmaf(wv, as2v[j], s1);
            s2 = fmaf(wv, ad2v[j], s2);
        }
        vs[k] = s1;
        vd[k] = s2;
    }
    __syncthreads();
    int lane = tid & 63, wv = tid >> 6;
    float scl = sc[lane], shl = sh[lane], vsl = vs[lane], vdl = vd[lane];
    float amax = -1e30f;
    int nwaves = gridDim.x * 4;
    for (int node = blockIdx.x * 4 + wv; node < n; node += nwaves) {
        float v = fmaf(feat[(size_t)node * 64 + lane], scl, shl);
        v = v > 0.f ? v : 0.f;
        z[(size_t)node * 64 + lane] = f2bf(v);
        float p1 = v * vsl, p2 = v * vdl;
#pragma unroll
        for (int o = 1; o < 64; o <<= 1) {
            p1 += __shfl_xor(p1, o, 64);
            p2 += __shfl_xor(p2, o, 64);
        }
        amax = fmaxf(amax, p1);
        if (lane == 0) { as_o[node] = p1; ad_o[node] = p2; }
    }
    if (lane == 0) atomicMax(menc_, enc_f(amax));
}

// ====== layer-2 gather: aligned 64-wide bf16 z, H=1; writes normalized agg (fp32) ======
__global__ void gatherz_kernel(const int* __restrict__ cnt,
                               const unsigned short* __restrict__ esrc,
                               const float* __restrict__ as_, const float* __restrict__ ad_,
                               const unsigned short* __restrict__ Z,
                               const unsigned* __restrict__ menc,
                               float* __restrict__ agg, int n) {
    __shared__ __align__(16) float comb[2][2][68];
    int tid = threadIdx.x;
    int wv = tid >> 6, lane = tid & 63;
    int ns = wv >> 1, ww = wv & 1;
    int slot = lane >> 4, ql = lane & 15;
    int node = blockIdx.x * 2 + ns;
    bool act = node < n;

    if (act) {
        int deg = cnt[node]; if (deg > CAP) deg = CAP;
        const unsigned short* ep = esrc + (size_t)node * CAP;
        float adv = ad_[node];
        float mm = dec_f(menc[0]) + adv;
        float mh = mm > 0.f ? mm : NEG_SLOPE * mm;

        float4 acc = make_float4(0.f, 0.f, 0.f, 0.f);
        int base = ww * 64;  // deg <= 128: one chunk per wave
        int lim = deg - base;
        if (lim > 64) lim = 64;
        if (lim < 0) lim = 0;
        int s = 0; float w = 0.f;
        if (lane < lim) {
            s = (int)ep[base + lane];
            float ev = as_[s] + adv;
            ev = ev > 0.f ? ev : NEG_SLOPE * ev;
            w = __expf(ev - mh);
        }
        float wp = w;
#pragma unroll
        for (int i = 0; i < 16; ++i) {
            if (i * 4 >= lim) break;
            int cj = i * 4 + slot;
            int sj = __shfl(s, cj, 64);
            float wj = __shfl(w, cj, 64);  // 0 past lim
            ushort4 hv = *(const ushort4*)(Z + (size_t)sj * 64 + ql * 4);
            acc.x = fmaf(bf2f(hv.x), wj, acc.x);
            acc.y = fmaf(bf2f(hv.y), wj, acc.y);
            acc.z = fmaf(bf2f(hv.z), wj, acc.z);
            acc.w = fmaf(bf2f(hv.w), wj, acc.w);
        }
#pragma unroll
        for (int o = 16; o < 64; o <<= 1) {
            acc.x += __shfl_xor(acc.x, o, 64);
            acc.y += __shfl_xor(acc.y, o, 64);
            acc.z += __shfl_xor(acc.z, o, 64);
            acc.w += __shfl_xor(acc.w, o, 64);
        }
#pragma unroll
        for (int o = 1; o < 64; o <<= 1) wp += __shfl_xor(wp, o, 64);
        if (slot == 0) *(float4*)&comb[ns][ww][ql * 4] = acc;
        if (lane == 0) comb[ns][ww][64] = wp;
    }
    __syncthreads();
    if (act && ww == 0) {
        float v = comb[ns][0][lane] + comb[ns][1][lane];
        float wsum = comb[ns][0][64] + comb[ns][1][64];
        agg[(size_t)node * 64 + lane] = v / (wsum + 1e-16f);
    }
}

// ====== layer-2 final: out = agg @ W2 + b2, fused log_softmax (barrier-free K-loop) ======
__global__ void gemm_lsm_kernel(const float* __restrict__ X, const float* __restrict__ W,
                                const float* __restrict__ bias, float* __restrict__ out, int n) {
    constexpr int K = 64, M = 40, KP = K + 2;
    __shared__ __align__(16) float Wt[M * KP];
    __shared__ __align__(16) float Xs[4][4 * K];
    int tid = threadIdx.x;
    for (int i = tid; i < K * M; i += 256) {
        int k = i / M, col = i - k * M;
        Wt[col * KP + k] = W[i];
    }
    __syncthreads();

    int lane = tid & 63, wv = tid >> 6;
    int col = (lane < M) ? lane : 0;
    float* Xw = Xs[wv];
    const float2* wcol = (const float2*)(Wt + col * KP);
    float bv = (lane < M) ? bias[lane] : 0.f;

    int nwaves = gridDim.x * 4;
    int ngroups = (n + 3) >> 2;

    for (int grp = blockIdx.x * 4 + wv; grp < ngroups; grp += nwaves) {
        int node0 = grp * 4;
        int nn = n - node0 < 4 ? n - node0 : 4;

        for (int v = lane; v < (nn * K) >> 2; v += 64)
            ((float4*)Xw)[v] = ((const float4*)(X + (size_t)node0 * K))[v];

        float acc[4] = {0.f, 0.f, 0.f, 0.f};
        for (int kk = 0; kk < K; kk += 4) {
            float2 w0 = wcol[kk >> 1];
            float2 w1 = wcol[(kk >> 1) + 1];
#pragma unroll
            for (int i = 0; i < 4; ++i) {
                float4 xv = *(const float4*)(Xw + i * K + kk);
                acc[i] = fmaf(xv.x, w0.x, acc[i]);
                acc[i] = fmaf(xv.y, w0.y, acc[i]);
                acc[i] = fmaf(xv.z, w1.x, acc[i]);
                acc[i] = fmaf(xv.w, w1.y, acc[i]);
            }
        }
#pragma unroll
        for (int i = 0; i < 4; ++i) {
            if (i >= nn) break;
            int node = node0 + i;
            float val = (lane < M) ? acc[i] + bv : -1e30f;
            float m2 = val;
#pragma unroll
            for (int o = 32; o > 0; o >>= 1) m2 = fmaxf(m2, __shfl_xor(m2, o, 64));
            float ex = (lane < M) ? __expf(val - m2) : 0.f;
#pragma unroll
            for (int o = 32; o > 0; o >>= 1) ex += __shfl_xor(ex, o, 64);
            if (lane < M) out[(size_t)node * M + lane] = val - m2 - logf(ex);
        }
    }
}

// ================= BN statistics =================
__global__ void bn_stats_kernel(const float* __restrict__ feat, float* bnsum, float* bnsq,
                                int n) {
    __shared__ float ls[256], lq[256];
    int f = threadIdx.x & 63, y = threadIdx.x >> 6;
    float ps = 0.f, pq = 0.f;
    for (int node = blockIdx.x * 4 + y; node < n; node += gridDim.x * 4) {
        float v = feat[(size_t)node * 64 + f];
        ps += v;
        pq += v * v;
    }
    ls[threadIdx.x] = ps;
    lq[threadIdx.x] = pq;
    __syncthreads();
    if (y == 0) {
        atomicAdd(&bnsum[f], ls[f] + ls[f + 64] + ls[f + 128] + ls[f + 192]);
        atomicAdd(&bnsq[f], lq[f] + lq[f + 64] + lq[f + 128] + lq[f + 192]);
    }
}

// ================= launch =================
extern "C" void kernel_launch(void* const* d_in, const int* in_sizes, int n_in,
                              void* d_out, int out_size, void* d_ws, size_t ws_size,
                              hipStream_t stream) {
    const float* x   = (const float*)d_in[0];
    const int*   ei  = (const int*)d_in[1];
    const float* W0  = (const float*)d_in[2];
    const float* as0 = (const float*)d_in[3];
    const float* ad0 = (const float*)d_in[4];
    const float* b0  = (const float*)d_in[5];
    const float* g0  = (const float*)d_in[6];
    const float* be0 = (const float*)d_in[7];
    const float* W1  = (const float*)d_in[8];
    const float* as1 = (const float*)d_in[9];
    const float* ad1 = (const float*)d_in[10];
    const float* b1  = (const float*)d_in[11];
    const float* g1  = (const float*)d_in[12];
    const float* be1 = (const float*)d_in[13];
    const float* W2  = (const float*)d_in[14];
    const float* as2 = (const float*)d_in[15];
    const float* ad2 = (const float*)d_in[16];
    const float* b2  = (const float*)d_in[17];

    const int N  = in_sizes[0] / 128;
    const int E  = in_sizes[1] / 2;
    const int EA = E + N;
    const int NBIN = (N + 127) >> 7;
    const int* srcs = ei;
    const int* dsts = ei + E;

    float* ws    = (float*)d_ws;
    float* feat  = ws;                          // N*64 f32
    float* agg   = feat + (size_t)N * 64;       // N*64 f32
    float* asrc  = agg + (size_t)N * 64;        // N*4
    float* adst  = asrc + (size_t)N * 4;        // N*4
    float* bn    = adst + (size_t)N * 4;        // 256
    unsigned* menc = (unsigned*)(bn + 256);     // 16
    int* bincnt  = (int*)(menc + 16);           // 512
    int* cnt     = bincnt + 512;                // N
    unsigned short* hb   = (unsigned short*)(cnt + N);        // N*64 bf16
    unsigned short* esrc = hb + (size_t)N * 64;               // N*CAP
    unsigned* binbuf = (unsigned*)(esrc + (size_t)N * CAP);   // NBIN*BCAP

    float* bn0sum = bn, *bn0sq = bn + 64, *bn1sum = bn + 128, *bn1sq = bn + 192;

    // ---- init + binned CSR build ----
    init_kernel<<<2, 256, 0, stream>>>(bincnt, bn, menc, NBIN);
    bin_kernel<<<512, 256, 0, stream>>>(srcs, dsts, E, EA, NBIN, bincnt, binbuf);
    build_kernel<<<NBIN, 256, 0, stream>>>(binbuf, bincnt, esrc, cnt, N);

    // ---- layer 0: 128 -> 64 (H=4,C=16) ----
    gemm_alpha_kernel<128, false><<<768, 256, 0, stream>>>(
        x, W0, as0, ad0, hb, asrc, adst, menc, N, nullptr, nullptr, nullptr, nullptr);
    gather64_kernel<<<nblk(N, 2), 256, 0, stream>>>(cnt, esrc, asrc, adst, hb, menc, b0, feat, N);
    bn_stats_kernel<<<512, 256, 0, stream>>>(feat, bn0sum, bn0sq, N);

    // ---- layer 1: 64 -> 64 (H=4,C=16); input BN+ReLU fused ----
    gemm_alpha_kernel<64, true><<<1024, 256, 0, stream>>>(
        feat, W1, as1, ad1, hb, asrc, adst, menc + 4, N, bn0sum, bn0sq, g0, be0);
    gather64_kernel<<<nblk(N, 2), 256, 0, stream>>>(cnt, esrc, asrc, adst, hb, menc + 4, b1,
                                                    feat, N);
    bn_stats_kernel<<<512, 256, 0, stream>>>(feat, bn1sum, bn1sq, N);

    // ---- layer 2: agg z then 64->40 GEMM + log_softmax ----
    prep2_kernel<<<512, 256, 0, stream>>>(feat, bn1sum, bn1sq, g1, be1, W2, as2, ad2,
                                          hb, asrc, adst, menc + 8, N);
    gatherz_kernel<<<nblk(N, 2), 256, 0, stream>>>(cnt, esrc, asrc, adst, hb, menc + 8, agg, N);
    gemm_lsm_kernel<<<1024, 256, 0, stream>>>(agg, W2, b2, (float*)d_out, N);
}

// Round 10
// 522.660 us; speedup vs baseline: 2.8658x; 2.8658x over previous
//
#include <hip/hip_runtime.h>
#include <math.h>

#define NEG_SLOPE 0.2f
#define CAP 128      // bucket capacity per dst (mean deg ~33)
#define BCAP 6144    // bin staging capacity (mean ~4350/bin)

// ---- monotonic float<->uint encoding for atomicMax on floats ----
__device__ __forceinline__ unsigned enc_f(float f) {
    unsigned b = __float_as_uint(f);
    return (b & 0x80000000u) ? ~b : (b | 0x80000000u);
}
__device__ __forceinline__ float dec_f(unsigned u) {
    return (u & 0x80000000u) ? __uint_as_float(u ^ 0x80000000u) : __uint_as_float(~u);
}
#define ENC_NEG_INF 0x007FFFFFu

// ---- bf16 pack/unpack (messages only; all accumulation fp32) ----
__device__ __forceinline__ unsigned short f2bf(float f) {
    unsigned u = __float_as_uint(f);
    u += 0x7fffu + ((u >> 16) & 1u);  // round-to-nearest-even
    return (unsigned short)(u >> 16);
}
__device__ __forceinline__ float bf2f(unsigned short b) {
    return __uint_as_float(((unsigned)b) << 16);
}

static inline int nblk(long total, int b) { return (int)((total + b - 1) / b); }

// =====================================================================================
// GEMM CODEGEN WARNING (R8/R9 post-mortem, measured):
//  * This R7-form gemm_alpha (KP=K+4, float4 W reads, per-trip __syncthreads, grid 512)
//    runs 67 us with FETCH ~13 MB / WRITE ~8.4 MB.
//  * The R8 "improvements" (KP=K+2 + float2 W reads + barrier-free K-loop + grid 768,
//    and/or __builtin_amdgcn_global_load_lds staging) produced ~670 us with 2.1 GB of
//    phantom HBM traffic (FETCH 878 MB / WRITE 1.2 GB, VALUBusy 2%) — scratch-spill-like
//    codegen. Reverting only global_load_lds did NOT fix it. DO NOT reapply any of these
//    to this kernel without isolating one at a time.
// =====================================================================================

// ================= init (ws poisoned 0xAA every call) =================
__global__ void init_kernel(int* bincnt, float* bn, unsigned* menc, int nbin) {
    int i = blockIdx.x * blockDim.x + threadIdx.x;
    if (i < nbin) bincnt[i] = 0;
    if (i < 256) bn[i] = 0.f;
    if (i < 16) menc[i] = ENC_NEG_INF;
}

// ================= pass 1: bin edges by dst>>7 =================
__global__ void bin_kernel(const int* __restrict__ srcs, const int* __restrict__ dsts,
                           int E_, int EA, int nbin, int* bincnt, unsigned* __restrict__ binbuf) {
    __shared__ int lh[512];
    __shared__ int lbase[512];
    int tid = threadIdx.x;
    for (int i = tid; i < nbin; i += 256) lh[i] = 0;
    __syncthreads();
    int chunk = (EA + gridDim.x - 1) / gridDim.x;
    int e0 = blockIdx.x * chunk;
    int e1 = e0 + chunk; if (e1 > EA) e1 = EA;
    for (int i = e0 + tid; i < e1; i += 256) {
        int d = (i < E_) ? dsts[i] : (i - E_);
        atomicAdd(&lh[d >> 7], 1);
    }
    __syncthreads();
    for (int i = tid; i < nbin; i += 256) {
        lbase[i] = atomicAdd(&bincnt[i], lh[i]);
        lh[i] = 0;
    }
    __syncthreads();
    for (int i = e0 + tid; i < e1; i += 256) {
        int s, d;
        if (i < E_) { s = srcs[i]; d = dsts[i]; } else { s = d = i - E_; }
        int b = d >> 7;
        int pos = lbase[b] + atomicAdd(&lh[b], 1);
        if (pos < BCAP) binbuf[(size_t)b * BCAP + pos] = ((unsigned)s << 16) | (unsigned)d;
    }
}

// ================= pass 2: per-bin bucket CSR in LDS =================
__global__ void build_kernel(const unsigned* __restrict__ binbuf, const int* __restrict__ bincnt,
                             unsigned short* __restrict__ esrc, int* __restrict__ cnt, int n) {
    __shared__ unsigned short slab[128 * CAP];  // 32 KB
    __shared__ int lcnt[128];
    int tid = threadIdx.x;
    int b = blockIdx.x, d0 = b << 7;
    if (tid < 128) lcnt[tid] = 0;
    __syncthreads();
    int nb = bincnt[b]; if (nb > BCAP) nb = BCAP;
    for (int i = tid; i < nb; i += 256) {
        unsigned u = binbuf[(size_t)b * BCAP + i];
        int s = (int)(u >> 16);
        int ld = (int)(u & 0xffffu) - d0;
        int pos = atomicAdd(&lcnt[ld], 1);
        if (pos < CAP) slab[ld * CAP + pos] = (unsigned short)s;
    }
    __syncthreads();
    const uint4* sl = (const uint4*)slab;
    uint4* outp = (uint4*)esrc;
    for (int i = tid; i < 128 * CAP / 8; i += 256) {
        int r = i >> 4;
        if (d0 + r < n) outp[(size_t)(d0 + r) * (CAP / 8) + (i & 15)] = sl[i];
    }
    if (tid < 128 && d0 + tid < n) cnt[d0 + tid] = lcnt[tid];
}

// ===== GEMM (fp32 in, BF16 out) + input-BN/ReLU + alpha epilogue + fused alpha-max =====
// Layers 0/1: M=64, H=4. Wave-tile 4 nodes x 64 cols. R7 form — see warning above.
template <int K, bool BN>
__global__ void gemm_alpha_kernel(const float* __restrict__ X, const float* __restrict__ W,
                                  const float* __restrict__ a_s, const float* __restrict__ a_d,
                                  unsigned short* __restrict__ Hout, float* __restrict__ as_o,
                                  float* __restrict__ ad_o, unsigned* menc_, int n,
                                  const float* __restrict__ bnsum,
                                  const float* __restrict__ bnsq,
                                  const float* __restrict__ g,
                                  const float* __restrict__ beta) {
    constexpr int M = 64, KP = K + 4;
    __shared__ __align__(16) float Wt[M * KP];
    __shared__ __align__(16) float scale[K];
    __shared__ __align__(16) float shift[K];
    __shared__ __align__(16) float Xs[4][4 * K];

    int tid = threadIdx.x;
    for (int i = tid; i < K * M; i += 256) {
        int k = i >> 6, col = i & 63;
        Wt[col * KP + k] = W[i];
    }
    if (BN) {
        float inv_n = 1.0f / (float)n;
        for (int i = tid; i < K; i += 256) {
            float mu = bnsum[i] * inv_n;
            float var = bnsq[i] * inv_n - mu * mu;
            float sc = rsqrtf(var + 1e-5f) * g[i];
            scale[i] = sc;
            shift[i] = beta[i] - mu * sc;
        }
    }
    __syncthreads();

    int lane = tid & 63, wv = tid >> 6;
    float asv = a_s[lane];
    float adv = a_d[lane];
    float* Xw = Xs[wv];
    const float* wcol = Wt + lane * KP;
    float amax = -1e30f;

    int nwaves = gridDim.x * 4;
    int gwave = blockIdx.x * 4 + wv;
    int ngroups = (n + 3) >> 2;
    int trips = (ngroups + nwaves - 1) / nwaves;  // uniform across all waves

    for (int t = 0; t < trips; ++t) {
        int grp = gwave + t * nwaves;
        bool active = grp < ngroups;
        int node0 = grp * 4;
        int nn = active ? (n - node0 < 4 ? n - node0 : 4) : 0;

        for (int v = lane; v < (nn * K) >> 2; v += 64) {
            float4 xv = ((const float4*)(X + (size_t)node0 * K))[v];
            if (BN) {
                int k4 = (v * 4) % K;
                float4 sc = *(const float4*)(scale + k4);
                float4 sh = *(const float4*)(shift + k4);
                xv.x = fmaf(xv.x, sc.x, sh.x); xv.x = xv.x > 0.f ? xv.x : 0.f;
                xv.y = fmaf(xv.y, sc.y, sh.y); xv.y = xv.y > 0.f ? xv.y : 0.f;
                xv.z = fmaf(xv.z, sc.z, sh.z); xv.z = xv.z > 0.f ? xv.z : 0.f;
                xv.w = fmaf(xv.w, sc.w, sh.w); xv.w = xv.w > 0.f ? xv.w : 0.f;
            }
            ((float4*)Xw)[v] = xv;
        }
        __syncthreads();  // uniform trip count -> non-divergent

        if (active) {
            float acc[4] = {0.f, 0.f, 0.f, 0.f};
            for (int kk = 0; kk < K; kk += 4) {
                float4 wv4 = *(const float4*)(wcol + kk);
#pragma unroll
                for (int i = 0; i < 4; ++i) {
                    float4 xv = *(const float4*)(Xw + i * K + kk);  // wave-uniform broadcast
                    acc[i] = fmaf(xv.x, wv4.x, acc[i]);
                    acc[i] = fmaf(xv.y, wv4.y, acc[i]);
                    acc[i] = fmaf(xv.z, wv4.z, acc[i]);
                    acc[i] = fmaf(xv.w, wv4.w, acc[i]);
                }
            }
#pragma unroll
            for (int i = 0; i < 4; ++i) {
                if (i >= nn) break;
                int node = node0 + i;
                Hout[(size_t)node * 64 + lane] = f2bf(acc[i]);
                float p1 = acc[i] * asv, p2 = acc[i] * adv;
#pragma unroll
                for (int o = 1; o < 16; o <<= 1) {
                    p1 += __shfl_xor(p1, o, 64);
                    p2 += __shfl_xor(p2, o, 64);
                }
                amax = fmaxf(amax, p1);
                if ((lane & 15) == 0) {
                    as_o[(size_t)node * 4 + (lane >> 4)] = p1;
                    ad_o[(size_t)node * 4 + (lane >> 4)] = p2;
                }
            }
        }
    }
    if ((lane & 15) == 0) atomicMax(&menc_[lane >> 4], enc_f(amax));
}

// ====== gather64: 2 waves/node, bf16 rows (128 B = one line), 4 edges/iter ======
__global__ void gather64_kernel(const int* __restrict__ cnt,
                                const unsigned short* __restrict__ esrc,
                                const float* __restrict__ as_, const float* __restrict__ ad_,
                                const unsigned short* __restrict__ Hf,
                                const unsigned* __restrict__ menc,
                                const float* __restrict__ bias, float* __restrict__ feat, int n) {
    __shared__ __align__(16) float comb[2][2][68];
    int tid = threadIdx.x;
    int wv = tid >> 6, lane = tid & 63;
    int ns = wv >> 1, ww = wv & 1;
    int slot = lane >> 4, ql = lane & 15, hq = ql >> 2;
    int node = blockIdx.x * 2 + ns;
    bool act = node < n;

    if (act) {
        int deg = cnt[node]; if (deg > CAP) deg = CAP;
        const unsigned short* ep = esrc + (size_t)node * CAP;
        float4 adv = *(const float4*)(ad_ + (size_t)node * 4);
        float adh = (slot == 0) ? adv.x : (slot == 1) ? adv.y : (slot == 2) ? adv.z : adv.w;
        float mm = dec_f(menc[slot]) + adh;  // shift >= true segment max
        float mh = mm > 0.f ? mm : NEG_SLOPE * mm;

        float4 acc = make_float4(0.f, 0.f, 0.f, 0.f);
        float wp = 0.f;
        for (int base = ww * 16; base < deg; base += 32) {
            int lim = deg - base; if (lim > 16) lim = 16;
            int s = 0; float w = 0.f;
            if (ql < lim) {
                s = (int)ep[base + ql];
                float ev = as_[(size_t)s * 4 + slot] + adh;
                ev = ev > 0.f ? ev : NEG_SLOPE * ev;
                w = __expf(ev - mh);
            }
            wp += w;
#pragma unroll
            for (int i = 0; i < 4; ++i) {
                int cj = i * 4 + slot;
                int sj = __shfl(s, cj, 64);
                float wj = __shfl(w, hq * 16 + cj, 64);  // 0 past lim
                ushort4 hv = *(const ushort4*)(Hf + (size_t)sj * 64 + ql * 4);
                acc.x = fmaf(bf2f(hv.x), wj, acc.x);
                acc.y = fmaf(bf2f(hv.y), wj, acc.y);
                acc.z = fmaf(bf2f(hv.z), wj, acc.z);
                acc.w = fmaf(bf2f(hv.w), wj, acc.w);
            }
        }
#pragma unroll
        for (int o = 16; o < 64; o <<= 1) {
            acc.x += __shfl_xor(acc.x, o, 64);
            acc.y += __shfl_xor(acc.y, o, 64);
            acc.z += __shfl_xor(acc.z, o, 64);
            acc.w += __shfl_xor(acc.w, o, 64);
        }
#pragma unroll
        for (int o = 1; o < 16; o <<= 1) wp += __shfl_xor(wp, o, 64);
        if (slot == 0) *(float4*)&comb[ns][ww][ql * 4] = acc;
        if (ql == 0) comb[ns][ww][64 + slot] = wp;
    }
    __syncthreads();
    if (act && ww == 0) {
        float v = comb[ns][0][lane] + comb[ns][1][lane];
        float wsum = comb[ns][0][64 + (lane >> 4)] + comb[ns][1][64 + (lane >> 4)];
        feat[(size_t)node * 64 + lane] = v / (wsum + 1e-16f) + bias[lane];
    }
}

// ====== layer-2 prep: z = relu(bn(feat)) in bf16; alpha = z . (W2@a); fused max ======
__global__ void prep2_kernel(const float* __restrict__ feat, const float* __restrict__ bnsum,
                             const float* __restrict__ bnsq, const float* __restrict__ g,
                             const float* __restrict__ beta, const float* __restrict__ W2,
                             const float* __restrict__ as2v, const float* __restrict__ ad2v,
                             unsigned short* __restrict__ z, float* __restrict__ as_o,
                             float* __restrict__ ad_o, unsigned* menc_, int n) {
    __shared__ float sc[64], sh[64], vs[64], vd[64];
    int tid = threadIdx.x;
    if (tid < 64) {
        float inv_n = 1.0f / (float)n;
        float mu = bnsum[tid] * inv_n;
        float var = bnsq[tid] * inv_n - mu * mu;
        float s = rsqrtf(var + 1e-5f) * g[tid];
        sc[tid] = s;
        sh[tid] = beta[tid] - mu * s;
    } else if (tid < 128) {
        int k = tid - 64;
        float s1 = 0.f, s2 = 0.f;
        for (int j = 0; j < 40; ++j) {
            float wv = W2[k * 40 + j];
            s1 = fmaf(wv, as2v[j], s1);
            s2 = fmaf(wv, ad2v[j], s2);
        }
        vs[k] = s1;
        vd[k] = s2;
    }
    __syncthreads();
    int lane = tid & 63, wv = tid >> 6;
    float scl = sc[lane], shl = sh[lane], vsl = vs[lane], vdl = vd[lane];
    float amax = -1e30f;
    int nwaves = gridDim.x * 4;
    for (int node = blockIdx.x * 4 + wv; node < n; node += nwaves) {
        float v = fmaf(feat[(size_t)node * 64 + lane], scl, shl);
        v = v > 0.f ? v : 0.f;
        z[(size_t)node * 64 + lane] = f2bf(v);
        float p1 = v * vsl, p2 = v * vdl;
#pragma unroll
        for (int o = 1; o < 64; o <<= 1) {
            p1 += __shfl_xor(p1, o, 64);
            p2 += __shfl_xor(p2, o, 64);
        }
        amax = fmaxf(amax, p1);
        if (lane == 0) { as_o[node] = p1; ad_o[node] = p2; }
    }
    if (lane == 0) atomicMax(menc_, enc_f(amax));
}

// ====== layer-2 gather: aligned 64-wide bf16 z, H=1; writes normalized agg (fp32) ======
__global__ void gatherz_kernel(const int* __restrict__ cnt,
                               const unsigned short* __restrict__ esrc,
                               const float* __restrict__ as_, const float* __restrict__ ad_,
                               const unsigned short* __restrict__ Z,
                               const unsigned* __restrict__ menc,
                               float* __restrict__ agg, int n) {
    __shared__ __align__(16) float comb[2][2][68];
    int tid = threadIdx.x;
    int wv = tid >> 6, lane = tid & 63;
    int ns = wv >> 1, ww = wv & 1;
    int slot = lane >> 4, ql = lane & 15;
    int node = blockIdx.x * 2 + ns;
    bool act = node < n;

    if (act) {
        int deg = cnt[node]; if (deg > CAP) deg = CAP;
        const unsigned short* ep = esrc + (size_t)node * CAP;
        float adv = ad_[node];
        float mm = dec_f(menc[0]) + adv;
        float mh = mm > 0.f ? mm : NEG_SLOPE * mm;

        float4 acc = make_float4(0.f, 0.f, 0.f, 0.f);
        int base = ww * 64;  // deg <= 128: one chunk per wave
        int lim = deg - base;
        if (lim > 64) lim = 64;
        if (lim < 0) lim = 0;
        int s = 0; float w = 0.f;
        if (lane < lim) {
            s = (int)ep[base + lane];
            float ev = as_[s] + adv;
            ev = ev > 0.f ? ev : NEG_SLOPE * ev;
            w = __expf(ev - mh);
        }
        float wp = w;
#pragma unroll
        for (int i = 0; i < 16; ++i) {
            if (i * 4 >= lim) break;
            int cj = i * 4 + slot;
            int sj = __shfl(s, cj, 64);
            float wj = __shfl(w, cj, 64);  // 0 past lim
            ushort4 hv = *(const ushort4*)(Z + (size_t)sj * 64 + ql * 4);
            acc.x = fmaf(bf2f(hv.x), wj, acc.x);
            acc.y = fmaf(bf2f(hv.y), wj, acc.y);
            acc.z = fmaf(bf2f(hv.z), wj, acc.z);
            acc.w = fmaf(bf2f(hv.w), wj, acc.w);
        }
#pragma unroll
        for (int o = 16; o < 64; o <<= 1) {
            acc.x += __shfl_xor(acc.x, o, 64);
            acc.y += __shfl_xor(acc.y, o, 64);
            acc.z += __shfl_xor(acc.z, o, 64);
            acc.w += __shfl_xor(acc.w, o, 64);
        }
#pragma unroll
        for (int o = 1; o < 64; o <<= 1) wp += __shfl_xor(wp, o, 64);
        if (slot == 0) *(float4*)&comb[ns][ww][ql * 4] = acc;
        if (lane == 0) comb[ns][ww][64] = wp;
    }
    __syncthreads();
    if (act && ww == 0) {
        float v = comb[ns][0][lane] + comb[ns][1][lane];
        float wsum = comb[ns][0][64] + comb[ns][1][64];
        agg[(size_t)node * 64 + lane] = v / (wsum + 1e-16f);
    }
}

// ====== layer-2 final: out = agg @ W2 + b2, fused log_softmax ======
__global__ void gemm_lsm_kernel(const float* __restrict__ X, const float* __restrict__ W,
                                const float* __restrict__ bias, float* __restrict__ out, int n) {
    constexpr int K = 64, M = 40, KP = K + 4;
    __shared__ __align__(16) float Wt[M * KP];
    __shared__ __align__(16) float Xs[4][4 * K];
    int tid = threadIdx.x;
    for (int i = tid; i < K * M; i += 256) {
        int k = i / M, col = i - k * M;
        Wt[col * KP + k] = W[i];
    }
    __syncthreads();

    int lane = tid & 63, wv = tid >> 6;
    int col = (lane < M) ? lane : 0;
    float* Xw = Xs[wv];
    const float* wcol = Wt + col * KP;
    float bv = (lane < M) ? bias[lane] : 0.f;

    int nwaves = gridDim.x * 4;
    int gwave = blockIdx.x * 4 + wv;
    int ngroups = (n + 3) >> 2;
    int trips = (ngroups + nwaves - 1) / nwaves;

    for (int t = 0; t < trips; ++t) {
        int grp = gwave + t * nwaves;
        bool active = grp < ngroups;
        int node0 = grp * 4;
        int nn = active ? (n - node0 < 4 ? n - node0 : 4) : 0;

        for (int v = lane; v < (nn * K) >> 2; v += 64)
            ((float4*)Xw)[v] = ((const float4*)(X + (size_t)node0 * K))[v];
        __syncthreads();

        if (active) {
            float acc[4] = {0.f, 0.f, 0.f, 0.f};
            for (int kk = 0; kk < K; kk += 4) {
                float4 wv4 = *(const float4*)(wcol + kk);
#pragma unroll
                for (int i = 0; i < 4; ++i) {
                    float4 xv = *(const float4*)(Xw + i * K + kk);
                    acc[i] = fmaf(xv.x, wv4.x, acc[i]);
                    acc[i] = fmaf(xv.y, wv4.y, acc[i]);
                    acc[i] = fmaf(xv.z, wv4.z, acc[i]);
                    acc[i] = fmaf(xv.w, wv4.w, acc[i]);
                }
            }
#pragma unroll
            for (int i = 0; i < 4; ++i) {
                if (i >= nn) break;
                int node = node0 + i;
                float val = (lane < M) ? acc[i] + bv : -1e30f;
                float m2 = val;
#pragma unroll
                for (int o = 32; o > 0; o >>= 1) m2 = fmaxf(m2, __shfl_xor(m2, o, 64));
                float ex = (lane < M) ? __expf(val - m2) : 0.f;
#pragma unroll
                for (int o = 32; o > 0; o >>= 1) ex += __shfl_xor(ex, o, 64);
                if (lane < M) out[(size_t)node * M + lane] = val - m2 - logf(ex);
            }
        }
    }
}

// ================= BN statistics =================
__global__ void bn_stats_kernel(const float* __restrict__ feat, float* bnsum, float* bnsq,
                                int n) {
    __shared__ float ls[256], lq[256];
    int f = threadIdx.x & 63, y = threadIdx.x >> 6;
    float ps = 0.f, pq = 0.f;
    for (int node = blockIdx.x * 4 + y; node < n; node += gridDim.x * 4) {
        float v = feat[(size_t)node * 64 + f];
        ps += v;
        pq += v * v;
    }
    ls[threadIdx.x] = ps;
    lq[threadIdx.x] = pq;
    __syncthreads();
    if (y == 0) {
        atomicAdd(&bnsum[f], ls[f] + ls[f + 64] + ls[f + 128] + ls[f + 192]);
        atomicAdd(&bnsq[f], lq[f] + lq[f + 64] + lq[f + 128] + lq[f + 192]);
    }
}

// ================= launch =================
extern "C" void kernel_launch(void* const* d_in, const int* in_sizes, int n_in,
                              void* d_out, int out_size, void* d_ws, size_t ws_size,
                              hipStream_t stream) {
    const float* x   = (const float*)d_in[0];
    const int*   ei  = (const int*)d_in[1];
    const float* W0  = (const float*)d_in[2];
    const float* as0 = (const float*)d_in[3];
    const float* ad0 = (const float*)d_in[4];
    const float* b0  = (const float*)d_in[5];
    const float* g0  = (const float*)d_in[6];
    const float* be0 = (const float*)d_in[7];
    const float* W1  = (const float*)d_in[8];
    const float* as1 = (const float*)d_in[9];
    const float* ad1 = (const float*)d_in[10];
    const float* b1  = (const float*)d_in[11];
    const float* g1  = (const float*)d_in[12];
    const float* be1 = (const float*)d_in[13];
    const float* W2  = (const float*)d_in[14];
    const float* as2 = (const float*)d_in[15];
    const float* ad2 = (const float*)d_in[16];
    const float* b2  = (const float*)d_in[17];

    const int N  = in_sizes[0] / 128;
    const int E  = in_sizes[1] / 2;
    const int EA = E + N;
    const int NBIN = (N + 127) >> 7;
    const int* srcs = ei;
    const int* dsts = ei + E;

    float* ws    = (float*)d_ws;
    float* feat  = ws;                          // N*64 f32
    float* agg   = feat + (size_t)N * 64;       // N*64 f32
    float* asrc  = agg + (size_t)N * 64;        // N*4
    float* adst  = asrc + (size_t)N * 4;        // N*4
    float* bn    = adst + (size_t)N * 4;        // 256
    unsigned* menc = (unsigned*)(bn + 256);     // 16
    int* bincnt  = (int*)(menc + 16);           // 512
    int* cnt     = bincnt + 512;                // N
    unsigned short* hb   = (unsigned short*)(cnt + N);        // N*64 bf16
    unsigned short* esrc = hb + (size_t)N * 64;               // N*CAP
    unsigned* binbuf = (unsigned*)(esrc + (size_t)N * CAP);   // NBIN*BCAP

    float* bn0sum = bn, *bn0sq = bn + 64, *bn1sum = bn + 128, *bn1sq = bn + 192;

    // ---- init + binned CSR build ----
    init_kernel<<<2, 256, 0, stream>>>(bincnt, bn, menc, NBIN);
    bin_kernel<<<512, 256, 0, stream>>>(srcs, dsts, E, EA, NBIN, bincnt, binbuf);
    build_kernel<<<NBIN, 256, 0, stream>>>(binbuf, bincnt, esrc, cnt, N);

    // ---- layer 0: 128 -> 64 (H=4,C=16) ----
    gemm_alpha_kernel<128, false><<<512, 256, 0, stream>>>(
        x, W0, as0, ad0, hb, asrc, adst, menc, N, nullptr, nullptr, nullptr, nullptr);
    gather64_kernel<<<nblk(N, 2), 256, 0, stream>>>(cnt, esrc, asrc, adst, hb, menc, b0, feat, N);
    bn_stats_kernel<<<512, 256, 0, stream>>>(feat, bn0sum, bn0sq, N);

    // ---- layer 1: 64 -> 64 (H=4,C=16); input BN+ReLU fused ----
    gemm_alpha_kernel<64, true><<<512, 256, 0, stream>>>(
        feat, W1, as1, ad1, hb, asrc, adst, menc + 4, N, bn0sum, bn0sq, g0, be0);
    gather64_kernel<<<nblk(N, 2), 256, 0, stream>>>(cnt, esrc, asrc, adst, hb, menc + 4, b1,
                                                    feat, N);
    bn_stats_kernel<<<512, 256, 0, stream>>>(feat, bn1sum, bn1sq, N);

    // ---- layer 2: agg z then 64->40 GEMM + log_softmax ----
    prep2_kernel<<<512, 256, 0, stream>>>(feat, bn1sum, bn1sq, g1, be1, W2, as2, ad2,
                                          hb, asrc, adst, menc + 8, N);
    gatherz_kernel<<<nblk(N, 2), 256, 0, stream>>>(cnt, esrc, asrc, adst, hb, menc + 8, agg, N);
    gemm_lsm_kernel<<<512, 256, 0, stream>>>(agg, W2, b2, (float*)d_out, N);
}